// Round 8
// baseline (99.803 us; speedup 1.0000x reference)
//
#include <hip/hip_runtime.h>

namespace {

typedef float v2f __attribute__((ext_vector_type(2)));

constexpr int T_LEN = 262144;   // samples per batch
constexpr int NF    = 1024;     // frames per batch
constexpr float INV1024 = 1.0f / 1024.0f;
constexpr int WSTRIDE = 68;     // floats per (kk,phase) row (64 + 4 pad)

// Single-wave workgroup: per-wave in-order LDS -> compiler fence only.
#define LDS_FENCE() asm volatile("" ::: "memory")

// Sum across each quad (4 overlap slots): two DPP quad_perm add stages.
__device__ __forceinline__ float qsum(float x) {
    x += __int_as_float(__builtin_amdgcn_update_dpp(
             0, __float_as_int(x), 0xB1, 0xF, 0xF, true));
    x += __int_as_float(__builtin_amdgcn_update_dpp(
             0, __float_as_int(x), 0x4E, 0xF, 0xF, true));
    return x;
}

template <bool CK>
__device__ __forceinline__ void ld4(const float* __restrict__ exb, int xi,
                                    float4 (&buf)[4]) {
    #pragma unroll
    for (int q = 0; q < 4; ++q) {
        const int idx = xi + q * 4;
        if (CK) {   // only wave 0 of a batch can touch idx<0; upper bound proven
            float4 v = make_float4(0.f, 0.f, 0.f, 0.f);
            if (idx >= 0) v = *(const float4*)(exb + idx);
            buf[q] = v;
        } else {
            buf[q] = *(const float4*)(exb + idx);
        }
    }
}

// 4 samples of order-22 IIR (transposed DF-II), fp32 state packed (s[j], s[j+11]).
__device__ __forceinline__ void iir4(const float4& x4, v2f (&sv)[11],
                                     const v2f (&mav)[11], float gv,
                                     float (&yo)[4]) {
    const float xv[4] = {x4.x, x4.y, x4.z, x4.w};
    #pragma unroll
    for (int u = 0; u < 4; ++u) {
        float y   = fmaf(gv, xv[u], sv[0].x);
        float s11 = sv[0].y;
        v2f yy = (v2f){y, y};
        #pragma unroll
        for (int j = 0; j < 10; ++j)
            sv[j] = __builtin_elementwise_fma(mav[j], yy, sv[j + 1]);
        sv[10].x = fmaf(mav[10].x, y, s11);
        sv[10].y = mav[10].y * y;
        yo[u] = y;
    }
}

__device__ __forceinline__ void procW(const float4 (&buf)[4], v2f (&sv)[11],
                                      const v2f (&mav)[11], float gv) {
    float yd[4];
    #pragma unroll
    for (int q = 0; q < 4; ++q) iir4(buf[q], sv, mav, gv, yd);
}

// Interior out sub-block (16 samples): LDS weights, DPP overlap-add, one
// lane (kk==sb) stores the task's float4s.
__device__ __forceinline__ void procOi(const float4 (&buf)[4], v2f (&sv)[11],
                                       const v2f (&mav)[11], float gv,
                                       const float* __restrict__ wrow, int t0,
                                       bool st, float* __restrict__ outp) {
    float4 w4[4];
    #pragma unroll
    for (int q = 0; q < 4; ++q) w4[q] = *(const float4*)(wrow + t0 + q * 4);
    #pragma unroll
    for (int q = 0; q < 4; ++q) {
        float y[4];
        iir4(buf[q], sv, mav, gv, y);
        const float wv[4] = {w4[q].x, w4[q].y, w4[q].z, w4[q].w};
        float o[4];
        #pragma unroll
        for (int u = 0; u < 4; ++u) o[u] = qsum(wv[u] * y[u]);
        if (st) *(float4*)(outp + q * 4) = make_float4(o[0], o[1], o[2], o[3]);
    }
}

// Edge out sub-block (32 of 4096 waves): per-sample cos, masked wsum, rcp.
__device__ __forceinline__ void procOe(const float4 (&buf)[4], v2f (&sv)[11],
                                       const v2f (&mav)[11], float gv,
                                       float& rev, float cA, float cB,
                                       bool st, float* __restrict__ outp) {
    #pragma unroll
    for (int q = 0; q < 4; ++q) {
        float y[4];
        iir4(buf[q], sv, mav, gv, y);
        float o[4];
        #pragma unroll
        for (int u = 0; u < 4; ++u) {
            float c  = __builtin_amdgcn_cosf(rev);  // cos(2*pi*rev)
            rev += INV1024;
            float wl = fmaf(cA, c, cB);             // mval * hann(m)
            o[u] = qsum(wl * y[u]) * __builtin_amdgcn_rcpf(qsum(wl));
        }
        if (st) *(float4*)(outp + q * 4) = make_float4(o[0], o[1], o[2], o[3]);
    }
}

// Per batch: 4096 output blocks of 64 samples (task n = 0..4095, out base n*64;
// padded block i = n+6). Quad slot kk runs frame f = (i>>2)-kk at frame-local
// start m0 = kk*256 + (i&3)*64, with 64 warm samples (zero-state; worst-case
// truncation ~1e-4, and m0=0 slots coincide with the true zero-state frame
// start). Per-lane serial work: 128 IIR steps (halved vs prior round).
__global__ __launch_bounds__(64, 4)
void lpc_ola_kernel(const float* __restrict__ ex,
                    const float* __restrict__ gain,
                    const float* __restrict__ a,
                    float* __restrict__ out)
{
    __shared__ __align__(16) float wq[16 * WSTRIDE];  // [kk*4+phase][64]

    const int lane = threadIdx.x;
    const int w    = blockIdx.x;
    const int wl   = w & 255;                 // wave-in-batch (256 waves/batch)
    const int b    = w >> 8;
    const bool chk  = (wl == 0);
    const bool edge = (wl == 0) | (wl == 255);

    // Weight table: wq[m>>6][m&63] = 0.25*(1-cos(2*pi*m/1024)); row r = m/64
    // matches (kk = r>>2, phase = r&3) since m0 = kk*256 + phase*64.
    #pragma unroll
    for (int ii = 0; ii < 16; ++ii) {
        int m = lane * 16 + ii;
        float c = __builtin_amdgcn_cosf((float)m * INV1024);
        wq[(m >> 6) * WSTRIDE + (m & 63)] = 0.25f * (1.0f - c);
    }
    LDS_FENCE();

    const int kk = lane & 3;          // overlap slot within quad
    const int jl = lane >> 2;         // task-in-wave
    const int n  = wl * 16 + jl;      // output 64-block within batch
    const int i  = n + 6;             // padded 64-block index
    const int ftop = i >> 2;
    const int f  = ftop - kk;
    const bool fv = (unsigned)f < (unsigned)NF;
    const int fc = fv ? f : 0;
    const float mval = fv ? 1.f : 0.f;
    const float gv   = fv ? gain[b * NF + fc] : 0.f;  // y=0 for invalid slots

    v2f mav[11];
    {
        const float2* ap = (const float2*)(a + (size_t)(b * NF + fc) * 22);
        float man[22];
        #pragma unroll
        for (int j = 0; j < 11; ++j) {
            float2 t = ap[j];
            man[2 * j] = -t.x; man[2 * j + 1] = -t.y;
        }
        #pragma unroll
        for (int j = 0; j < 11; ++j) mav[j] = (v2f){man[j], man[j + 11]};
    }
    v2f sv[11];
    #pragma unroll
    for (int j = 0; j < 11; ++j) sv[j] = (v2f){0.f, 0.f};

    const float* exb = ex + (size_t)b * T_LEN;
    int xi = n * 64 - 64;                        // first warm sample (kk-indep)
    const int ph  = i & 3;
    const int m0k = kk * 256 + (ph << 6);        // frame-local idx of out sample 0
    const float* wrow = wq + (((kk << 2) | ph) * WSTRIDE);
    float rev = (float)m0k * INV1024;            // edge path only
    const float cA = -0.5f * mval, cB = 0.5f * mval;
    float* outp0 = out + (size_t)b * T_LEN + (size_t)n * 64;

    float4 A[4], B[4], C[4], D[4];

    // preload all 4 warm sub-blocks (64 samples, depth-4 pipeline fill)
    if (chk) {
        ld4<true>(exb, xi, A); ld4<true>(exb, xi + 16, B);
        ld4<true>(exb, xi + 32, C); ld4<true>(exb, xi + 48, D);
    } else {
        ld4<false>(exb, xi, A); ld4<false>(exb, xi + 16, B);
        ld4<false>(exb, xi + 32, C); ld4<false>(exb, xi + 48, D);
    }
    xi += 64;   // = n*64: out-phase refills are always in-bounds

    // ---- warm (64 samples), refilling with the 4 out sub-blocks ----
    procW(A, sv, mav, gv); ld4<false>(exb, xi,      A);
    procW(B, sv, mav, gv); ld4<false>(exb, xi + 16, B);
    procW(C, sv, mav, gv); ld4<false>(exb, xi + 32, C);
    procW(D, sv, mav, gv); ld4<false>(exb, xi + 48, D);

    // ---- out (64 samples = 4 sub-blocks of 16) ----
    if (!edge) {
        procOi(A, sv, mav, gv, wrow,  0, kk == 0, outp0);
        procOi(B, sv, mav, gv, wrow, 16, kk == 1, outp0 + 16);
        procOi(C, sv, mav, gv, wrow, 32, kk == 2, outp0 + 32);
        procOi(D, sv, mav, gv, wrow, 48, kk == 3, outp0 + 48);
    } else {
        procOe(A, sv, mav, gv, rev, cA, cB, kk == 0, outp0);
        procOe(B, sv, mav, gv, rev, cA, cB, kk == 1, outp0 + 16);
        procOe(C, sv, mav, gv, rev, cA, cB, kk == 2, outp0 + 32);
        procOe(D, sv, mav, gv, rev, cA, cB, kk == 3, outp0 + 48);
    }
}

} // namespace

extern "C" void kernel_launch(void* const* d_in, const int* in_sizes, int n_in,
                              void* d_out, int out_size, void* d_ws, size_t ws_size,
                              hipStream_t stream)
{
    (void)in_sizes; (void)n_in; (void)out_size; (void)d_ws; (void)ws_size;
    const float* ex   = (const float*)d_in[0];
    const float* gain = (const float*)d_in[1];
    const float* a    = (const float*)d_in[2];
    float* out        = (float*)d_out;

    dim3 grid(4096);   // 16 batches x 256 waves; 4 waves/SIMD
    dim3 block(64);
    hipLaunchKernelGGL(lpc_ola_kernel, grid, block, 0, stream, ex, gain, a, out);
}